// Round 6
// baseline (249.653 us; speedup 1.0000x reference)
//
#include <hip/hip_runtime.h>
#include <float.h>

#define NB 64  // n_bins (bins array has NB+1 edges)

typedef float vfloat4 __attribute__((ext_vector_type(4)));

// Persistent software-pipelined version. Each block owns gridDim-strided tiles
// of 1024 consecutive float4-slots (256 threads x 4 slots at +256 stride,
// perfectly coalesced 1KB/wave stores). Per iteration: issue next tile's 4
// x-loads FIRST, then compute+store the current tile. Loads thus retire one
// full iteration ahead; stores are never waited on (vmcnt counts in issue
// order, loads are always older than the trailing stores at each wait).
__global__ __launch_bounds__(256) void ple_kernel(const float* __restrict__ x,
                                                  const float* __restrict__ bins,
                                                  float* __restrict__ out,
                                                  long long total4) {
    __shared__ __align__(16) float s_rinv[NB];
    __shared__ __align__(16) float s_nlor[NB];
    __shared__ __align__(16) float s_cl[NB];
    __shared__ __align__(16) float s_ch[NB];

    const int tid = threadIdx.x;
    if (tid < NB) {
        const float lo   = bins[tid];
        const float hi   = bins[tid + 1];
        const float rinv = 1.0f / (hi - lo);   // once per block, off the hot path
        s_rinv[tid] = rinv;
        s_nlor[tid] = -lo * rinv;
        s_cl[tid] = (tid == 0)      ? -FLT_MAX : 0.0f;   // bin 0: no left clamp
        s_ch[tid] = (tid == NB - 1) ?  FLT_MAX : 1.0f;   // bin 63: no right clamp
    }
    __syncthreads();

    const int j4 = (tid & 15) << 2;            // this thread's 4 bins (invariant)
    const vfloat4 rinv4 = *(const vfloat4*)&s_rinv[j4];
    const vfloat4 nlor4 = *(const vfloat4*)&s_nlor[j4];
    const vfloat4 cl4   = *(const vfloat4*)&s_cl[j4];
    const vfloat4 ch4   = *(const vfloat4*)&s_ch[j4];

    const long long tile_stride = (long long)gridDim.x * 1024;
    long long b = (long long)blockIdx.x * 1024 + tid;
    if (b >= total4) return;

    // Prologue: loads for tile 0.
    float xv[4];
#pragma unroll
    for (int k = 0; k < 4; ++k) {
        const long long t = b + (long long)(k << 8);
        xv[k] = (t < total4) ? x[t >> 4] : 0.0f;
    }

    for (; b < total4; b += tile_stride) {
        const long long nb = b + tile_stride;

        // Issue next tile's loads BEFORE this tile's stores.
        float xn[4];
#pragma unroll
        for (int k = 0; k < 4; ++k) {
            const long long t = nb + (long long)(k << 8);
            xn[k] = (t < total4) ? x[t >> 4] : 0.0f;
        }

        // Compute + store current tile (waits only on xv's loads, issued an
        // iteration ago; trailing stores stay in flight).
#pragma unroll
        for (int k = 0; k < 4; ++k) {
            const long long t = b + (long long)(k << 8);
            vfloat4 r;
#pragma unroll
            for (int c = 0; c < 4; ++c) {
                const float v = fmaf(xv[k], rinv4[c], nlor4[c]);
                r[c] = fminf(fmaxf(v, cl4[c]), ch4[c]);
            }
            if (t < total4)
                *((vfloat4*)out + t) = r;
        }

#pragma unroll
        for (int k = 0; k < 4; ++k) xv[k] = xn[k];
    }
}

extern "C" void kernel_launch(void* const* d_in, const int* in_sizes, int n_in,
                              void* d_out, int out_size, void* d_ws, size_t ws_size,
                              hipStream_t stream) {
    const float* x    = (const float*)d_in[0];
    const float* bins = (const float*)d_in[1];
    float* out        = (float*)d_out;

    const int batch = in_sizes[0];                   // x is (BATCH, 1)
    const long long total4 = (long long)batch * (NB / 4);

    // 15625 tiles of 1024 slots for BATCH=1e6; grid 3125 -> exactly 5 tiles
    // per block, uniform control flow across all waves.
    const long long tiles = (total4 + 1023) / 1024;
    long long grid = (tiles + 4) / 5;
    if (grid > tiles) grid = tiles;

    ple_kernel<<<(dim3)(unsigned)grid, 256, 0, stream>>>(x, bins, out, total4);
}